// Round 5
// baseline (154.563 us; speedup 1.0000x reference)
//
#include <hip/hip_runtime.h>
#include <math.h>

typedef float f32x2 __attribute__((ext_vector_type(2)));
typedef float f32x4 __attribute__((ext_vector_type(4)));

constexpr int NPTS  = 16384;        // P == G
constexpr int BLOCK = 256;
constexpr int T     = 8;            // A-points per thread
constexpr int ABLK  = BLOCK * T;    // 2048 A-points per block
constexpr int XBLK  = NPTS / ABLK;  // 8 blocks along A
constexpr int SPLIT = 64;           // B splits
constexpr int CHUNK = NPTS / SPLIT; // 256 B-points per chunk (== BLOCK)
constexpr unsigned NB_DIR = XBLK * SPLIT;  // 512 blocks per direction

static_assert(CHUNK == BLOCK, "staging assumes one B point per thread");

// v_pk_fma_f32 (VOP3P, CDNA2+): d.lo = a.lo*b.lo + c.lo; d.hi = a.hi*b.hi + c.hi
// ALL source operands must be 64-bit VGPR pairs (single-VGPR src rejected).
__device__ __forceinline__ f32x2 pk_fma(f32x2 a, f32x2 b, f32x2 c) {
    f32x2 d;
    asm("v_pk_fma_f32 %0, %1, %2, %3"
        : "=v"(d) : "v"(a), "v"(b), "v"(c));
    return d;
}

// ---------------------------------------------------------------------------
// Init: min arrays to 0xFFFFFFFF (uint-max; real d2 bits < 0x80000000 so
// uint atomicMin orders correctly), tickets to 0. accum needs no init
// (written by atomicExch before any read).
// ---------------------------------------------------------------------------
__global__ __launch_bounds__(BLOCK) void init_kernel(
    uint4* __restrict__ minAll, unsigned* __restrict__ tickets)
{
    int i = blockIdx.x * BLOCK + threadIdx.x;   // 2*NPTS/4 = 8192 uint4
    minAll[i] = make_uint4(~0u, ~0u, ~0u, ~0u);
    if (i < 3) tickets[i] = 0u;
}

// ---------------------------------------------------------------------------
// Fully fused Chamfer kernel. blockIdx.z = direction (0: pred->gt, 1: gt->pred).
//  - stages B chunk into SoA LDS with on-the-fly (-2x,-2y,-2z,b2) packing
//  - register-tiles 8 A points/thread; coords pre-duplicated into f32x2 pairs
//  - inner loop per 4 B x 8 A: 6 v_pk_fma_f32 + 3 min = 2.25 inst-slots/pair
//  - uint atomicMin to global min arrays
//  - per-direction ticket: last block of each direction does that direction's
//    weighted reduction (benign atomic-RMW reads = cross-XCD coherent);
//    second finisher writes the final scalar.
// ---------------------------------------------------------------------------
__global__ __launch_bounds__(BLOCK, 4) void chamfer_kernel(
    const float* __restrict__ pred, const float* __restrict__ gt,
    const float* __restrict__ wpred, const float* __restrict__ wgt,
    unsigned* __restrict__ minP, unsigned* __restrict__ minG,
    float* __restrict__ accum, unsigned* __restrict__ tickets,
    float* __restrict__ outp)
{
    const int dir = blockIdx.z;
    const float* Araw = (dir == 0) ? pred : gt;
    const float* Braw = (dir == 0) ? gt : pred;
    unsigned*    omin = (dir == 0) ? minP : minG;

    __shared__ __align__(16) float sx[CHUNK], sy[CHUNK], sz[CHUNK], sw[CHUNK];

    const int t     = threadIdx.x;
    const int aBase = blockIdx.x * ABLK;
    const int b0    = blockIdx.y * CHUNK;

    // Stage B chunk: one point per thread, pack (-2x,-2y,-2z, b2) into SoA.
    {
        int bi = b0 + t;
        float bx = Braw[3*bi], by = Braw[3*bi+1], bz = Braw[3*bi+2];
        sx[t] = -2.0f * bx;
        sy[t] = -2.0f * by;
        sz[t] = -2.0f * bz;
        sw[t] = fmaf(bx, bx, fmaf(by, by, bz * bz));
    }

    // A register tile: 8 points/thread, coords duplicated into pairs for VOP3P.
    f32x2 axp[T], ayp[T], azp[T];
    float a2[T];
    #pragma unroll
    for (int k = 0; k < T; ++k) {
        int ai = aBase + k * BLOCK + t;
        float x = Araw[3*ai], y = Araw[3*ai+1], z = Araw[3*ai+2];
        axp[k] = (f32x2){x, x};
        ayp[k] = (f32x2){y, y};
        azp[k] = (f32x2){z, z};
        a2[k]  = fmaf(x, x, fmaf(y, y, z * z));
    }
    __syncthreads();

    float mn[T];
    #pragma unroll
    for (int k = 0; k < T; ++k) mn[k] = INFINITY;

    const f32x4* SX = (const f32x4*)sx;
    const f32x4* SY = (const f32x4*)sy;
    const f32x4* SZ = (const f32x4*)sz;
    const f32x4* SW = (const f32x4*)sw;

    for (int j = 0; j < CHUNK / 4; ++j) {
        f32x4 X = SX[j], Y = SY[j], Z = SZ[j], W = SW[j];   // 4 ds_read_b128
        f32x2 xlo = __builtin_shufflevector(X, X, 0, 1);
        f32x2 xhi = __builtin_shufflevector(X, X, 2, 3);
        f32x2 ylo = __builtin_shufflevector(Y, Y, 0, 1);
        f32x2 yhi = __builtin_shufflevector(Y, Y, 2, 3);
        f32x2 zlo = __builtin_shufflevector(Z, Z, 0, 1);
        f32x2 zhi = __builtin_shufflevector(Z, Z, 2, 3);
        f32x2 wlo = __builtin_shufflevector(W, W, 0, 1);
        f32x2 whi = __builtin_shufflevector(W, W, 2, 3);
        #pragma unroll
        for (int k = 0; k < T; ++k) {
            f32x2 d0 = pk_fma(zlo, azp[k], wlo);
            d0 = pk_fma(ylo, ayp[k], d0);
            d0 = pk_fma(xlo, axp[k], d0);
            f32x2 d1 = pk_fma(zhi, azp[k], whi);
            d1 = pk_fma(yhi, ayp[k], d1);
            d1 = pk_fma(xhi, axp[k], d1);
            // d = b2 - 2 a.b for 4 B-points; fold to v_min3
            mn[k] = fminf(fminf(fminf(d0.x, d0.y), fminf(d1.x, d1.y)), mn[k]);
        }
    }

    #pragma unroll
    for (int k = 0; k < T; ++k) {
        float d = fmaxf(a2[k] + mn[k], 0.0f);   // clamp commutes with min
        atomicMin(&omin[aBase + k * BLOCK + t], __float_as_uint(d));
    }

    // ---- per-direction completion ticket --------------------------------
    __threadfence();          // release this thread's atomicMins
    __syncthreads();          // all lanes fenced before t0 tickets
    __shared__ unsigned last;
    if (t == 0) last = atomicAdd(&tickets[dir], 1u);
    __syncthreads();

    if (last == NB_DIR - 1) {
        // Last block of this direction: full weighted reduction.
        const float* w = (dir == 0) ? wpred : wgt;
        float num = 0.0f, den = 0.0f;
        for (int i = t; i < NPTS; i += BLOCK) {
            unsigned mb = atomicOr(&omin[i], 0u);   // coherent RMW read
            float wv = w[i];
            num = fmaf(wv, __uint_as_float(mb), num);
            den += wv;
        }
        for (int off = 32; off > 0; off >>= 1) {
            num += __shfl_down(num, off);
            den += __shfl_down(den, off);
        }
        __shared__ float rn[BLOCK / 64], rd[BLOCK / 64];
        int wid = t >> 6, lane = t & 63;
        if (lane == 0) { rn[wid] = num; rd[wid] = den; }
        __syncthreads();
        if (t == 0) {
            float tn = rn[0] + rn[1] + rn[2] + rn[3];
            float td = rd[0] + rd[1] + rd[2] + rd[3];
            atomicExch(&accum[2*dir],     tn);      // coherent store
            atomicExch(&accum[2*dir + 1], td);
            __threadfence();
            unsigned o = atomicAdd(&tickets[2], 1u);
            if (o == 1) {                           // second finisher
                unsigned* ua = (unsigned*)accum;
                float n0 = __uint_as_float(atomicOr(&ua[0], 0u));
                float d0 = __uint_as_float(atomicOr(&ua[1], 0u));
                float n1 = __uint_as_float(atomicOr(&ua[2], 0u));
                float d1 = __uint_as_float(atomicOr(&ua[3], 0u));
                outp[0] = n0 / fmaxf(d0, 1e-9f) + n1 / fmaxf(d1, 1e-9f);
            }
        }
    }
}

// ---------------------------------------------------------------------------
extern "C" void kernel_launch(void* const* d_in, const int* in_sizes, int n_in,
                              void* d_out, int out_size, void* d_ws, size_t ws_size,
                              hipStream_t stream)
{
    const float* pred  = (const float*)d_in[0];   // (P,3)
    const float* gt    = (const float*)d_in[1];   // (G,3)
    const float* wpred = (const float*)d_in[2];   // (P,)
    const float* wgt   = (const float*)d_in[3];   // (G,)
    float* out = (float*)d_out;

    // ws layout: minP | minG | accum[4] | tickets[3]
    unsigned* minP    = (unsigned*)d_ws;
    unsigned* minG    = minP + NPTS;
    float*    accum   = (float*)(minG + NPTS);
    unsigned* tickets = (unsigned*)(accum + 4);

    init_kernel<<<(2 * NPTS / 4) / BLOCK, BLOCK, 0, stream>>>(
        (uint4*)minP, tickets);

    dim3 grid(XBLK, SPLIT, 2);   // 8 x 64 x 2 = 1024 blocks
    chamfer_kernel<<<grid, BLOCK, 0, stream>>>(
        pred, gt, wpred, wgt, minP, minG, accum, tickets, out);
}